// Round 11
// baseline (308.483 us; speedup 1.0000x reference)
//
#include <hip/hip_runtime.h>
#include <stdint.h>

// FC tensor product, f16, MFMA f32_16x16x32_f16.
// R11 = R10 with the w110 grid/index bug fixed (2176 blocks, bijective jobs).
// ZERO-LDS streaming GEMM (AITER pattern). 2176 single-wave jobs (64 thr).
// Per wave: b-tile + a-octets + 4-slot W register ring, W streamed
// global->VGPR (consumed once; ring refill after MFMA consume, WAR-ordered),
// compiler-managed waitcnt. No LDS, no barriers, no atomics. w110/w101 write
// f16 slabs folded by ep_add; all other outputs stored directly exactly once.

typedef _Float16 f16;
typedef f16 f16x8 __attribute__((ext_vector_type(8)));
typedef float f32x4 __attribute__((ext_vector_type(4)));

#define OFF_W000 0u               // [h2][u128*4+vq][q4][n64][8]
#define OFF_W110 2097152u         // [h2][u64*2+p][q][n64][8]  (1/sqrt3 folded)
#define OFF_W011 2621440u         // [u128*2+p][q][n64][8]
#define OFF_W101 3145728u         // [s2u128*2+p][q][n64][8]   (transposed)
#define OFF_W111 3670016u         // [u64*2+p][q][n64][8]
#define OFF_XS1  3932160u         // [o16][r8192][8]
#define OFF_XS2  4980736u
#define OFF_XV1  6029312u         // [i3][o8][r8192][8]
#define OFF_XV2  7602176u
#define OFF_S110 9175040u         // 6 x 524288 f16  (i*2+h)
#define OFF_S101 12320768u        // 3 x 524288
#define WS_ELEMS 13893632u        // ~27.8 MB

#define SC_0E 0.006987712429686843f
#define SC_1O 0.0078125f
#define SC_1E 0.011048543456039806f

// ---------------- pre-kernel: retile everything to f16 ----------------
// total threads = 9175040 = 35840 * 256 (every branch bound exact)
__global__ void tile_all_k(const float* __restrict__ w000, const float* __restrict__ w011,
                           const float* __restrict__ w101, const float* __restrict__ w110,
                           const float* __restrict__ w111, const float* __restrict__ x1,
                           const float* __restrict__ x2, f16* __restrict__ ws)
{
  unsigned tid = blockIdx.x*256u + threadIdx.x;
  if (tid < 2097152u) {  // W000s [h][u][vq][q][n64][8], v = vq*32+q*8+e
    unsigned e=tid&7u, n=(tid>>3)&63u, q=(tid>>9)&3u, vq=(tid>>11)&3u,
             u=(tid>>13)&127u, h=tid>>20;
    unsigned v = vq*32u + q*8u + e;
    ws[OFF_W000+tid] = (f16)w000[u*16384u + v*128u + h*64u + n];
    return;
  }
  tid -= 2097152u;
  if (tid < 524288u) {   // W110s [h][u][p][q][n64][8], fold 1/sqrt3
    unsigned e=tid&7u, n=(tid>>3)&63u, q=(tid>>9)&3u, p=(tid>>11)&1u,
             u=(tid>>12)&63u, h=tid>>18;
    unsigned v = p*32u + q*8u + e;
    ws[OFF_W110+tid] = (f16)(w110[u*8192u + v*128u + h*64u + n] * 0.5773502691896258f);
    return;
  }
  tid -= 524288u;
  if (tid < 524288u) {   // W011s [u][p][q][n64][8]
    unsigned e=tid&7u, n=(tid>>3)&63u, q=(tid>>9)&3u, p=(tid>>11)&1u, u=tid>>12;
    unsigned v = p*32u + q*8u + e;
    ws[OFF_W011+tid] = (f16)w011[u*4096u + v*64u + n];
    return;
  }
  tid -= 524288u;
  if (tid < 524288u) {   // W101s [u=s2][p][q][n64][8]  (transposed source)
    unsigned e=tid&7u, n=(tid>>3)&63u, q=(tid>>9)&3u, p=(tid>>11)&1u, u=tid>>12;
    unsigned v = p*32u + q*8u + e;   // v1 index
    ws[OFF_W101+tid] = (f16)w101[v*8192u + u*64u + n];
    return;
  }
  tid -= 524288u;
  if (tid < 262144u) {   // W111s [u][p][q][n64][8]
    unsigned e=tid&7u, n=(tid>>3)&63u, q=(tid>>9)&3u, p=(tid>>11)&1u, u=tid>>12;
    unsigned v = p*32u + q*8u + e;
    ws[OFF_W111+tid] = (f16)w111[u*4096u + v*64u + n];
    return;
  }
  tid -= 262144u;
  if (tid < 1048576u) {  // XS1 [o16][r8192][8]
    unsigned e=tid&7u, r=(tid>>3)&8191u, o=tid>>16;
    ws[OFF_XS1+tid] = (f16)x1[r*320u + o*8u + e];
    return;
  }
  tid -= 1048576u;
  if (tid < 1048576u) {  // XS2
    unsigned e=tid&7u, r=(tid>>3)&8191u, o=tid>>16;
    ws[OFF_XS2+tid] = (f16)x2[r*320u + o*8u + e];
    return;
  }
  tid -= 1048576u;
  if (tid < 1572864u) {  // XV1 [i3][o8][r8192][8]
    unsigned e=tid&7u, r=(tid>>3)&8191u, o=(tid>>16)&7u, i=tid>>19;
    ws[OFF_XV1+tid] = (f16)x1[r*320u + 128u + (o*8u+e)*3u + i];
    return;
  }
  tid -= 1572864u;
  {                      // XV2
    unsigned e=tid&7u, r=(tid>>3)&8191u, o=(tid>>16)&7u, i=tid>>19;
    ws[OFF_XV2+tid] = (f16)x2[r*320u + 128u + (o*8u+e)*3u + i];
  }
}

// ---------------- main kernel ----------------
// One stream-phase: SS supersteps x L steps, L = 8*VQ2.  Step t: u = t/VQ2,
// vq = t%VQ2 (compile-time within superstep).  Per step: af = a[row,u]*br[vq]
// (VALU), 16 MFMA consuming W-ring slot kc&3, then refill slot with W(t+4)
// (WAR dependency orders refill after consume; compiler emits counted vmcnt).
template<int VQ2, int SS, bool NEG>
__device__ __forceinline__ void run_stream(
    const f16* __restrict__ W, const f16* __restrict__ aP,
    const f16* __restrict__ bP, int rowb, int lane, f32x4 (&acc)[4][4])
{
  constexpr int L = 8*VQ2;
  const int q = lane >> 4, r15 = lane & 15;
  const int rbase = rowb + r15;

  // b-tile -> registers (whole phase)
  f16x8 br[4][VQ2];
#pragma unroll
  for (int mt=0; mt<4; ++mt)
#pragma unroll
    for (int vq=0; vq<VQ2; ++vq)
      br[mt][vq] = *(const f16x8*)(bP + (unsigned)((vq*4+q)*8192 + rbase + mt*16)*8u);

  // W register ring: 4 slots x 4 n-frags (64 VGPR)
  const f16* Wl = W + (q*64 + r15)*8;
  f16x8 ring[4][4];
#pragma unroll
  for (int s=0; s<4; ++s)
#pragma unroll
    for (int nt=0; nt<4; ++nt)
      ring[s][nt] = *(const f16x8*)(Wl + s*2048 + nt*128);

  // a-octet (8 u) -> registers, double-buffered across supersteps
  f16x8 aR[4], aRn[4];
#pragma unroll
  for (int mt=0; mt<4; ++mt)
    aR[mt] = *(const f16x8*)(aP + (unsigned)(rbase + mt*16)*8u);

#pragma unroll 1
  for (int ss = 0; ss < SS-1; ++ss) {
    const f16* Wss = Wl + (unsigned)(ss*L)*2048u;
    const f16* An  = aP + (unsigned)((ss+1)*8192)*8u;
#pragma unroll
    for (int kc = 0; kc < L; ++kc) {
      if (kc == L-6) {                      // prefetch next superstep's a-octet
#pragma unroll
        for (int mt=0; mt<4; ++mt)
          aRn[mt] = *(const f16x8*)(An + (unsigned)(rbase + mt*16)*8u);
      }
      f16x8 af[4];
#pragma unroll
      for (int mt=0; mt<4; ++mt) {
        f16 av = aR[mt][kc/VQ2];
        if constexpr (NEG) av = -av;
        af[mt] = av * br[mt][kc%VQ2];
      }
#pragma unroll
      for (int nt=0; nt<4; ++nt)
#pragma unroll
        for (int mt=0; mt<4; ++mt)
          acc[mt][nt] = __builtin_amdgcn_mfma_f32_16x16x32_f16(af[mt], ring[kc&3][nt], acc[mt][nt], 0,0,0);
      // refill consumed slot with W(t+4)  (WAR: ordered after the MFMAs above)
#pragma unroll
      for (int nt=0; nt<4; ++nt)
        ring[kc&3][nt] = *(const f16x8*)(Wss + (kc+4)*2048 + nt*128);
    }
#pragma unroll
    for (int mt=0; mt<4; ++mt) aR[mt] = aRn[mt];
  }
  {  // last superstep: no a-prefetch; refill only while t+4 < M
    const f16* Wss = Wl + (unsigned)((SS-1)*L)*2048u;
#pragma unroll
    for (int kc = 0; kc < L; ++kc) {
      f16x8 af[4];
#pragma unroll
      for (int mt=0; mt<4; ++mt) {
        f16 av = aR[mt][kc/VQ2];
        if constexpr (NEG) av = -av;
        af[mt] = av * br[mt][kc%VQ2];
      }
#pragma unroll
      for (int nt=0; nt<4; ++nt)
#pragma unroll
        for (int mt=0; mt<4; ++mt)
          acc[mt][nt] = __builtin_amdgcn_mfma_f32_16x16x32_f16(af[mt], ring[kc&3][nt], acc[mt][nt], 0,0,0);
      if (kc < L-4) {
#pragma unroll
        for (int nt=0; nt<4; ++nt)
          ring[kc&3][nt] = *(const f16x8*)(Wss + (kc+4)*2048 + nt*128);
      }
    }
  }
}

__global__ __launch_bounds__(64, 2)
void tp_main(f16* __restrict__ ws, float* __restrict__ out)
{
  const int lane = threadIdx.x & 63;
  const int q = lane >> 4, r15 = lane & 15;

  f32x4 acc[4][4];
#pragma unroll
  for (int a=0; a<4; ++a)
#pragma unroll
    for (int b=0; b<4; ++b) acc[a][b] = (f32x4){0.f,0.f,0.f,0.f};

  // 2176 blocks = 8 XCD-groups x 272 jobs, bijective per bucket:
  // per x: 32 w000(512 steps) + 48 w011 + 48 w101 + 48 w111 (256) + 96 w110 (128)
  // = 65536 K-steps per XCD; big jobs dispatch first, w110 fills the tail.
  const int x = blockIdx.x & 7, r = blockIdx.x >> 3;

#define STORE_DIRECT(col_expr, SC)                                        \
  _Pragma("unroll")                                                       \
  for (int mt=0;mt<4;++mt)                                                \
    _Pragma("unroll")                                                     \
    for (int nt=0;nt<4;++nt)                                              \
      _Pragma("unroll")                                                   \
      for (int rg=0;rg<4;++rg)                                            \
        out[(unsigned)(rowb+mt*16+q*4+rg)*512u + (unsigned)(col_expr)] = (SC)*acc[mt][nt][rg];

#define STORE_SLAB(base, SC)                                              \
  _Pragma("unroll")                                                       \
  for (int mt=0;mt<4;++mt)                                                \
    _Pragma("unroll")                                                     \
    for (int nt=0;nt<4;++nt)                                              \
      _Pragma("unroll")                                                   \
      for (int rg=0;rg<4;++rg)                                            \
        ws[(base) + (unsigned)(rowb+mt*16+q*4+rg)*64u + (unsigned)(nt*16+r15)] \
            = (f16)((SC)*acc[mt][nt][rg]);

  if (r < 32) {            // ---- w000: direct out0 partial (sole w000 writer)
    const int j = x*32 + r, h = j >> 7, rg = j & 127;   // j in [0,256)
    const int rowb = rg*64;
    run_stream<4,16,false>(ws + OFF_W000 + (unsigned)h*1048576u,
                           ws + OFF_XS1, ws + OFF_XS2, rowb, lane, acc);
    STORE_DIRECT(h*64 + nt*16 + r15, SC_0E)
  } else if (r < 80) {     // ---- w011 (a=s1, b=v2_i): direct out1o partial
    const int j = x*48 + (r-32), i = j/128, rg = j%128;  // j in [0,384)
    const int rowb = rg*64;
    run_stream<2,16,false>(ws + OFF_W011, ws + OFF_XS1,
                           ws + OFF_XV2 + (unsigned)i*524288u, rowb, lane, acc);
    STORE_DIRECT(128 + 3*(nt*16+r15) + i, SC_1O)
  } else if (r < 128) {    // ---- w101 (a=s2, b=v1_i): slab
    const int j = x*48 + (r-80), i = j/128, rg = j%128;  // j in [0,384)
    const int rowb = rg*64;
    run_stream<2,16,false>(ws + OFF_W101, ws + OFF_XS2,
                           ws + OFF_XV1 + (unsigned)i*524288u, rowb, lane, acc);
    STORE_SLAB(OFF_S101 + (unsigned)i*524288u, SC_1O)
  } else if (r < 176) {    // ---- w111 cross comp kk (2 signed terms): direct
    const int j = x*48 + (r-128), kk = j/128, rg = j%128;  // j in [0,384)
    const int rowb = rg*64;
    int i = kk+1; if (i>2) i-=3;
    int jj = kk+2; if (jj>2) jj-=3;
    run_stream<2,8,false>(ws + OFF_W111, ws + OFF_XV1 + (unsigned)i*524288u,
                          ws + OFF_XV2 + (unsigned)jj*524288u, rowb, lane, acc);
    run_stream<2,8,true>(ws + OFF_W111, ws + OFF_XV1 + (unsigned)jj*524288u,
                         ws + OFF_XV2 + (unsigned)i*524288u, rowb, lane, acc);
    STORE_DIRECT(320 + 3*(nt*16+r15) + kk, SC_1E)
  } else {                 // ---- w110' comp i, n-half h: slab (96 per x, exact)
    const int j = x*96 + (r-176);                        // j in [0,768) bijective
    const int h = j/384, t2 = j%384, i = t2/128, rg = t2%128;
    const int rowb = rg*64;
    run_stream<2,8,false>(ws + OFF_W110 + (unsigned)h*262144u,
                          ws + OFF_XV1 + (unsigned)i*524288u,
                          ws + OFF_XV2 + (unsigned)i*524288u, rowb, lane, acc);
    STORE_SLAB(OFF_S110 + (unsigned)(i*2+h)*524288u, SC_0E)
  }
#undef STORE_DIRECT
#undef STORE_SLAB
}

// ---------------- epilogue: fold f16 slabs into out ----------------
__global__ void ep_add(const f16* __restrict__ ws, float* __restrict__ out)
{
  unsigned tid = blockIdx.x*256u + threadIdx.x;   // 2621440 = 10240*256 exactly
  unsigned r = tid/320u, c = tid - r*320u;
  if (c < 128u) {
    unsigned h = c>>6, cc = c&63u;
    float s = (float)ws[OFF_S110 + (0u*2u+h)*524288u + r*64u + cc]
            + (float)ws[OFF_S110 + (1u*2u+h)*524288u + r*64u + cc]
            + (float)ws[OFF_S110 + (2u*2u+h)*524288u + r*64u + cc];
    out[r*512u + c] += s;
  } else {
    unsigned t = c - 128u;
    unsigned n = (t*21846u)>>16, i = t - n*3u;
    out[r*512u + c] += (float)ws[OFF_S101 + i*524288u + r*64u + n];
  }
}

extern "C" void kernel_launch(void* const* d_in, const int* in_sizes, int n_in,
                              void* d_out, int out_size, void* d_ws, size_t ws_size,
                              hipStream_t stream)
{
  const float* x1   = (const float*)d_in[0];
  const float* x2   = (const float*)d_in[1];
  const float* w000 = (const float*)d_in[2];
  const float* w011 = (const float*)d_in[3];
  const float* w101 = (const float*)d_in[4];
  const float* w110 = (const float*)d_in[5];
  const float* w111 = (const float*)d_in[6];
  float* out = (float*)d_out;
  f16* ws   = (f16*)d_ws;

  if (ws_size < (size_t)WS_ELEMS * 2) return;   // ~27.8 MB scratch

  tile_all_k<<<35840, 256, 0, stream>>>(w000, w011, w101, w110, w111, x1, x2, ws);
  tp_main<<<2176, 64, 0, stream>>>(ws, out);
  ep_add<<<10240, 256, 0, stream>>>(ws, out);
}